// Round 4
// baseline (439.099 us; speedup 1.0000x reference)
//
#include <hip/hip_runtime.h>
#include <hip/hip_bf16.h>

#define NPTS 200000
#define CIN 64
#define KOFF 27
#define MTILE 128

typedef __attribute__((ext_vector_type(8))) short bf16x8;
typedef __attribute__((ext_vector_type(4))) float f32x4;

__device__ inline void gload16(const void* g, void* lds) {
  __builtin_amdgcn_global_load_lds(
      (const __attribute__((address_space(1))) void*)g,
      (__attribute__((address_space(3))) void*)lds, 16, 0, 0);
}

__device__ inline ushort f2bf(float f) {
  union { float f; unsigned u; } x; x.f = f;
  unsigned r = (x.u + 0x7fffu + ((x.u >> 16) & 1u)) >> 16;
  return (ushort)r;
}

// feats fp32 -> bf16, n divisible by 4
__global__ void cvt_bf16_kernel(const float* __restrict__ in,
                                ushort* __restrict__ out, int n4) {
  int stride = gridDim.x * blockDim.x;
  for (int i = blockIdx.x * blockDim.x + threadIdx.x; i < n4; i += stride) {
    float4 v = ((const float4*)in)[i];
    ushort4 o;
    o.x = f2bf(v.x); o.y = f2bf(v.y); o.z = f2bf(v.z); o.w = f2bf(v.w);
    ((ushort4*)out)[i] = o;
  }
}

// W[k][c][co] fp32 -> Wt[k][co][c] bf16
__global__ void cvt_wt_kernel(const float* __restrict__ W,
                              ushort* __restrict__ Wt, int Co) {
  int total = KOFF * CIN * Co;
  for (int i = blockIdx.x * blockDim.x + threadIdx.x; i < total;
       i += gridDim.x * blockDim.x) {
    int k = i / (CIN * Co);
    int rem = i - k * (CIN * Co);
    int co = rem / CIN;
    int c = rem - co * CIN;
    Wt[i] = f2bf(W[k * CIN * Co + c * Co + co]);
  }
}

// One sparse-conv layer: out[j] = sum_k feats[nbr[j,k]] @ W[k] + b  (opt relu)
// inB: N x 64 bf16;  Wt: 27 x COUT x 64 bf16 (transposed);  bias fp32
template <int COUT, bool RELU, bool OUTBF16>
__global__ __launch_bounds__(256, 2)
void layer_kernel(const ushort* __restrict__ inB,
                  const ushort* __restrict__ Wt,
                  const float* __restrict__ bias,
                  const int* __restrict__ nbr,
                  void* __restrict__ outp,
                  const ushort* __restrict__ zpage) {
  __shared__ ushort A_lds[MTILE * CIN];   // 16 KB, xor-swizzled chunks
  __shared__ ushort B_lds[COUT * CIN];    // 8/16 KB, xor-swizzled
  __shared__ int nbr_lds[MTILE * KOFF];   // 13.5 KB

  const int tid = threadIdx.x;
  const int j0 = blockIdx.x * MTILE;

  for (int idx = tid; idx < MTILE * KOFF; idx += 256) {
    int j = j0 + idx / KOFF;
    nbr_lds[idx] = (j < NPTS) ? nbr[j0 * KOFF + idx] : -1;
  }
  __syncthreads();

  const int w = tid >> 6, l = tid & 63;
  const int llo = l & 15, lhi = l >> 4;

  constexpr int NF = COUT / 16;
  f32x4 acc[2][NF];
  const f32x4 zero4 = {0.f, 0.f, 0.f, 0.f};
#pragma unroll
  for (int m = 0; m < 2; ++m)
#pragma unroll
    for (int n = 0; n < NF; ++n) acc[m][n] = zero4;

  constexpr int AR = (MTILE * CIN * 2) / (256 * 16);  // 4 rounds of 16B/thread
  constexpr int BR = (COUT * CIN * 2) / (256 * 16);   // 2 or 4

  for (int k = 0; k < KOFF; ++k) {
    // ---- stage A (gathered rows, zero page for missing neighbors) ----
#pragma unroll
    for (int p = 0; p < AR; ++p) {
      int lin = p * 256 + tid;       // 16B-chunk linear index
      int row = lin >> 3;
      int c = lin & 7;
      int csw = c ^ (row & 7);       // inverse-swizzled SOURCE chunk
      int src = nbr_lds[row * KOFF + k];
      const ushort* g = (src < 0) ? (zpage + csw * 8)
                                  : (inB + src * CIN + csw * 8);
      gload16(g, &A_lds[lin * 8]);
    }
    // ---- stage B = Wt[k] (linear, swizzled source) ----
#pragma unroll
    for (int p = 0; p < BR; ++p) {
      int lin = p * 256 + tid;
      int row = lin >> 3;
      int c = lin & 7;
      int csw = c ^ (row & 7);
      gload16(Wt + k * COUT * CIN + row * CIN + csw * 8, &B_lds[lin * 8]);
    }
    __syncthreads();

#pragma unroll
    for (int kk = 0; kk < 2; ++kk) {
      bf16x8 a[2];
#pragma unroll
      for (int m = 0; m < 2; ++m) {
        int row = w * 32 + m * 16 + llo;
        int chunk = (kk * 4 + lhi) ^ (row & 7);
        a[m] = *(const bf16x8*)&A_lds[row * CIN + chunk * 8];
      }
#pragma unroll
      for (int n = 0; n < NF; ++n) {
        int brow = n * 16 + llo;
        int chunk = (kk * 4 + lhi) ^ (brow & 7);
        bf16x8 b = *(const bf16x8*)&B_lds[brow * CIN + chunk * 8];
#pragma unroll
        for (int m = 0; m < 2; ++m)
          acc[m][n] = __builtin_amdgcn_mfma_f32_16x16x32_bf16(a[m], b,
                                                              acc[m][n], 0, 0, 0);
      }
    }
    __syncthreads();
  }

  // ---- epilogue: bias, relu, store ----
#pragma unroll
  for (int n = 0; n < NF; ++n) {
    int col = n * 16 + llo;
    float bb = bias[col];
#pragma unroll
    for (int m = 0; m < 2; ++m) {
#pragma unroll
      for (int r = 0; r < 4; ++r) {
        int row = j0 + w * 32 + m * 16 + lhi * 4 + r;
        if (row < NPTS) {
          float x = acc[m][n][r] + bb;
          if (RELU) x = fmaxf(x, 0.f);
          if (OUTBF16)
            ((ushort*)outp)[row * COUT + col] = f2bf(x);
          else
            ((float*)outp)[row * COUT + col] = x;
        }
      }
    }
  }
}

extern "C" void kernel_launch(void* const* d_in, const int* in_sizes, int n_in,
                              void* d_out, int out_size, void* d_ws, size_t ws_size,
                              hipStream_t stream) {
  const float* feats = (const float*)d_in[0];
  const float* W1 = (const float*)d_in[1];
  const float* b1 = (const float*)d_in[2];
  const float* W2 = (const float*)d_in[3];
  const float* b2 = (const float*)d_in[4];
  const float* W3 = (const float*)d_in[5];
  const float* b3 = (const float*)d_in[6];
  const int* nbr = (const int*)d_in[7];

  // d_out (102.4MB fp32) doubles as scratch early in the pipeline:
  //   featsB (bf16, 25.6MB) at offset 0      -- dead after layer 1
  //   h1B    (bf16, 25.6MB) at offset 76.8MB -- dead after layer 2
  // ws layout (small, always-read buffers FIRST for OOB safety):
  //   W1t 0.5MB | W2t 0.5MB | W3t 1MB | zpage 256B | h2B 25.6MB  (~27.7MB)
  char* ws = (char*)d_ws;
  ushort* featsB = (ushort*)d_out;
  ushort* h1B = (ushort*)((char*)d_out + 76800000);
  ushort* W1t = (ushort*)(ws);
  ushort* W2t = (ushort*)(ws + 262144);
  ushort* W3t = (ushort*)(ws + 524288);
  ushort* zpage = (ushort*)(ws + 1048576);
  ushort* h2B = (ushort*)(ws + 2097152);

  hipMemsetAsync(zpage, 0, 256, stream);

  cvt_bf16_kernel<<<2048, 256, 0, stream>>>(feats, featsB, NPTS * CIN / 4);
  cvt_wt_kernel<<<256, 256, 0, stream>>>(W1, W1t, 64);
  cvt_wt_kernel<<<256, 256, 0, stream>>>(W2, W2t, 64);
  cvt_wt_kernel<<<512, 256, 0, stream>>>(W3, W3t, 128);

  int grid = (NPTS + MTILE - 1) / MTILE;
  layer_kernel<64, true, true><<<grid, 256, 0, stream>>>(featsB, W1t, b1, nbr, h1B, zpage);
  layer_kernel<64, true, true><<<grid, 256, 0, stream>>>(h1B, W2t, b2, nbr, h2B, zpage);
  layer_kernel<128, false, false><<<grid, 256, 0, stream>>>(h2B, W3t, b3, nbr, d_out, zpage);
}